// Round 1
// baseline (374.090 us; speedup 1.0000x reference)
//
#include <hip/hip_runtime.h>
#include <hip/hip_bf16.h>
#include <stdint.h>

#define DIM 2048
#define NH 16
#define NKV 4
#define HD 128
#define BATCH 2
#define SEQ 2048
#define NQKV (DIM + 2*NKV*HD)   // 3072

typedef unsigned short ushort_t;
typedef __attribute__((ext_vector_type(8))) short short8;
typedef __attribute__((ext_vector_type(4))) float f32x4;

__device__ inline ushort_t f2b(float f) {
    union { float f; uint32_t u; } v; v.f = f;
    uint32_t r = (v.u + 0x7fffu + ((v.u >> 16) & 1u)) >> 16;
    return (ushort_t)r;
}

__global__ void cast_f32_bf16(const float* __restrict__ in, ushort_t* __restrict__ out, int n4) {
    int i = blockIdx.x * blockDim.x + threadIdx.x;
    if (i < n4) {
        float4 v = ((const float4*)in)[i];
        ushort4 o;
        o.x = f2b(v.x); o.y = f2b(v.y); o.z = f2b(v.z); o.w = f2b(v.w);
        ((ushort4*)out)[i] = o;
    }
}

__device__ inline void gload_lds16(const ushort_t* g, ushort_t* l) {
    __builtin_amdgcn_global_load_lds((const __attribute__((address_space(1))) void*)g,
                                     (__attribute__((address_space(3))) void*)l, 16, 0, 0);
}

// C[m][n] = sum_k A[m][k] * B[n][k]   (A: MxK row-major bf16, B: NxK row-major bf16, C fp32)
__launch_bounds__(256, 2)
__global__ void gemm_bt(const ushort_t* __restrict__ A, const ushort_t* __restrict__ Bm,
                        float* __restrict__ C, int M, int N, int K) {
    __shared__ ushort_t lA[128 * 32];
    __shared__ ushort_t lB[128 * 32];
    const int t = threadIdx.x;
    const int lane = t & 63;
    const int w = t >> 6;
    const int wr = w >> 1, wc = w & 1;
    const int g = lane >> 4, l16 = lane & 15;
    const int m0 = blockIdx.y * 128, n0 = blockIdx.x * 128;

    f32x4 acc[4][4];
#pragma unroll
    for (int i = 0; i < 4; i++)
#pragma unroll
        for (int j = 0; j < 4; j++) acc[i][j] = (f32x4){0, 0, 0, 0};

    const int row_a = t >> 2;          // 0..63
    const int col_a = (t & 3) * 8;
    const int nk = K >> 5;

    for (int kt = 0; kt < nk; ++kt) {
        const int k0 = kt * 32;
        gload_lds16(A + (size_t)(m0 + row_a) * K + k0 + col_a,       lA + t * 8);
        gload_lds16(A + (size_t)(m0 + 64 + row_a) * K + k0 + col_a,  lA + 2048 + t * 8);
        gload_lds16(Bm + (size_t)(n0 + row_a) * K + k0 + col_a,      lB + t * 8);
        gload_lds16(Bm + (size_t)(n0 + 64 + row_a) * K + k0 + col_a, lB + 2048 + t * 8);
        __syncthreads();
        short8 af[4], bf[4];
#pragma unroll
        for (int i = 0; i < 4; i++) {
            af[i] = *(const short8*)(lA + (wr * 64 + i * 16 + l16) * 32 + g * 8);
            bf[i] = *(const short8*)(lB + (wc * 64 + i * 16 + l16) * 32 + g * 8);
        }
#pragma unroll
        for (int i = 0; i < 4; i++)
#pragma unroll
            for (int j = 0; j < 4; j++)
                acc[i][j] = __builtin_amdgcn_mfma_f32_16x16x32_bf16(af[i], bf[j], acc[i][j], 0, 0, 0);
        __syncthreads();
    }
#pragma unroll
    for (int i = 0; i < 4; i++)
#pragma unroll
        for (int j = 0; j < 4; j++) {
            int rb = m0 + wr * 64 + i * 16 + g * 4;
            int cb = n0 + wc * 64 + j * 16 + l16;
#pragma unroll
            for (int r = 0; r < 4; r++)
                C[(size_t)(rb + r) * N + cb] = acc[i][j][r];
        }
}

// one wave per (token, head24): h24 in [0,16)=q, [16,20)=k, [20,24)=v
__global__ void normrope(const float* __restrict__ cq, const float* __restrict__ qgain,
                         ushort_t* __restrict__ qb, ushort_t* __restrict__ kb, ushort_t* __restrict__ vb) {
    int bidx = blockIdx.x;
    int h24 = bidx % 24;
    int tok = bidx / 24;            // b*SEQ + s
    int s = tok % SEQ, b = tok / SEQ;
    int lane = threadIdx.x;         // 0..63
    const float* row = cq + (size_t)tok * NQKV + h24 * HD;
    float x1 = row[lane];
    float x2 = row[lane + 64];
    if (h24 >= NH + NKV) {          // v head: plain cast
        int kvh = h24 - (NH + NKV);
        ushort_t* dst = vb + ((size_t)(b * NKV + kvh) * SEQ + s) * HD;
        dst[lane] = f2b(x1);
        dst[lane + 64] = f2b(x2);
        return;
    }
    float ss = x1 * x1 + x2 * x2;
#pragma unroll
    for (int off = 32; off; off >>= 1) ss += __shfl_xor(ss, off, 64);
    float r = rsqrtf(ss * (1.0f / 128.0f) + 1.1920929e-07f);
    x1 *= r; x2 *= r;
    float inv = exp2f(-(float)lane * (13.287712379549449f / 64.0f));
    float ang = (float)s * inv;
    float c = cosf(ang), sn = sinf(ang);
    float o1 = x1 * c + x2 * sn;
    float o2 = -x1 * sn + x2 * c;
    if (h24 < NH) {
        float gsc = qgain[h24] * 0.08838834764831845f;   // gain * 1/sqrt(HD)
        o1 *= gsc; o2 *= gsc;
        ushort_t* dst = qb + ((size_t)(b * NH + h24) * SEQ + s) * HD;
        dst[lane] = f2b(o1); dst[lane + 64] = f2b(o2);
    } else {
        int kvh = h24 - NH;
        ushort_t* dst = kb + ((size_t)(b * NKV + kvh) * SEQ + s) * HD;
        dst[lane] = f2b(o1); dst[lane + 64] = f2b(o2);
    }
}

#define KT 32
#define KLD 136   // K tile row stride (elems), 272B = 16B aligned, padded
#define VLD 40    // Vt row stride, 80B = 16B aligned, padded
#define PLD 40

__launch_bounds__(256, 2)
__global__ void attn(const ushort_t* __restrict__ qb, const ushort_t* __restrict__ kb,
                     const ushort_t* __restrict__ vb, ushort_t* __restrict__ yb) {
    __shared__ ushort_t Klds[KT * KLD];
    __shared__ ushort_t Vt[HD * VLD];
    __shared__ ushort_t Plds[4][16 * PLD];

    const int qtile = blockIdx.x;
    const int bh = blockIdx.y;
    const int b = bh / NH, h = bh % NH;
    const int kvh = h >> 2;
    const int t = threadIdx.x;
    const int w = t >> 6, lane = t & 63;
    const int g = lane >> 4, l16 = lane & 15;
    const int qw = qtile * 64 + w * 16;

    const ushort_t* Qp = qb + (size_t)(b * NH + h) * SEQ * HD;
    const ushort_t* Kp = kb + (size_t)(b * NKV + kvh) * SEQ * HD;
    const ushort_t* Vp = vb + (size_t)(b * NKV + kvh) * SEQ * HD;

    short8 aq[4];
#pragma unroll
    for (int ds = 0; ds < 4; ds++)
        aq[ds] = *(const short8*)(Qp + (size_t)(qw + l16) * HD + ds * 32 + g * 8);

    f32x4 y[8];
#pragma unroll
    for (int i = 0; i < 8; i++) y[i] = (f32x4){0, 0, 0, 0};
    float mrow[4] = {-1e30f, -1e30f, -1e30f, -1e30f};
    float lrow[4] = {0, 0, 0, 0};

    const int ntiles = qtile * 2 + 2;
    const int skv = t >> 3;           // K stage: row 0..31
    const int sc = (t & 7) * 16;      // K stage: col
    const int vkv = t & 31;           // V stage: kv col
    const int vdc = (t >> 5) * 16;    // V stage: d chunk

    for (int kt = 0; kt < ntiles; ++kt) {
        const int kv0 = kt * KT;
        __syncthreads();
        {   // stage K [32][128] -> padded rows
            const ushort_t* src = Kp + (size_t)(kv0 + skv) * HD + sc;
            *(short8*)(Klds + skv * KLD + sc)     = *(const short8*)(src);
            *(short8*)(Klds + skv * KLD + sc + 8) = *(const short8*)(src + 8);
        }
        {   // stage V transposed: Vt[d][kv]
            const ushort_t* src = Vp + (size_t)(kv0 + vkv) * HD + vdc;
            short8 v0 = *(const short8*)(src);
            short8 v1 = *(const short8*)(src + 8);
#pragma unroll
            for (int j = 0; j < 8; j++) Vt[(vdc + j) * VLD + vkv] = (ushort_t)v0[j];
#pragma unroll
            for (int j = 0; j < 8; j++) Vt[(vdc + 8 + j) * VLD + vkv] = (ushort_t)v1[j];
        }
        __syncthreads();

        f32x4 sacc[2];
        sacc[0] = (f32x4){0, 0, 0, 0};
        sacc[1] = (f32x4){0, 0, 0, 0};
#pragma unroll
        for (int ds = 0; ds < 4; ds++) {
            short8 bk0 = *(const short8*)(Klds + l16 * KLD + ds * 32 + g * 8);
            short8 bk1 = *(const short8*)(Klds + (16 + l16) * KLD + ds * 32 + g * 8);
            sacc[0] = __builtin_amdgcn_mfma_f32_16x16x32_bf16(aq[ds], bk0, sacc[0], 0, 0, 0);
            sacc[1] = __builtin_amdgcn_mfma_f32_16x16x32_bf16(aq[ds], bk1, sacc[1], 0, 0, 0);
        }
        // causal mask + running max
        float tm[4];
#pragma unroll
        for (int r = 0; r < 4; r++) {
            int q = qw + g * 4 + r;
            if (kv0 + l16 > q)      sacc[0][r] = -1e30f;
            if (kv0 + 16 + l16 > q) sacc[1][r] = -1e30f;
            tm[r] = fmaxf(sacc[0][r], sacc[1][r]);
        }
#pragma unroll
        for (int r = 0; r < 4; r++)
#pragma unroll
            for (int mask = 1; mask < 16; mask <<= 1)
                tm[r] = fmaxf(tm[r], __shfl_xor(tm[r], mask, 64));
        float al[4], rs[4];
#pragma unroll
        for (int r = 0; r < 4; r++) {
            float mn = fmaxf(mrow[r], tm[r]);
            al[r] = __expf(mrow[r] - mn);
            mrow[r] = mn;
            float p0 = __expf(sacc[0][r] - mn);
            float p1 = __expf(sacc[1][r] - mn);
            sacc[0][r] = p0; sacc[1][r] = p1;
            rs[r] = p0 + p1;
        }
#pragma unroll
        for (int r = 0; r < 4; r++) {
#pragma unroll
            for (int mask = 1; mask < 16; mask <<= 1)
                rs[r] += __shfl_xor(rs[r], mask, 64);
            lrow[r] = lrow[r] * al[r] + rs[r];
        }
#pragma unroll
        for (int i = 0; i < 8; i++)
#pragma unroll
            for (int r = 0; r < 4; r++) y[i][r] *= al[r];
        // P (C-layout) -> LDS as bf16 in A-layout order
        ushort_t* P = Plds[w];
#pragma unroll
        for (int r = 0; r < 4; r++) {
            P[(g * 4 + r) * PLD + l16]      = f2b(sacc[0][r]);
            P[(g * 4 + r) * PLD + 16 + l16] = f2b(sacc[1][r]);
        }
        asm volatile("s_waitcnt lgkmcnt(0)" ::: "memory");
        short8 pa = *(const short8*)(P + l16 * PLD + g * 8);
#pragma unroll
        for (int ni = 0; ni < 8; ni++) {
            short8 bv = *(const short8*)(Vt + (ni * 16 + l16) * VLD + g * 8);
            y[ni] = __builtin_amdgcn_mfma_f32_16x16x32_bf16(pa, bv, y[ni], 0, 0, 0);
        }
    }
    float rl[4];
#pragma unroll
    for (int r = 0; r < 4; r++) rl[r] = 1.0f / lrow[r];
    ushort_t* Yp = yb + (size_t)b * SEQ * DIM;
#pragma unroll
    for (int ni = 0; ni < 8; ni++)
#pragma unroll
        for (int r = 0; r < 4; r++) {
            int q = qw + g * 4 + r;
            Yp[(size_t)q * DIM + h * HD + ni * 16 + l16] = f2b(y[ni][r] * rl[r]);
        }
}

extern "C" void kernel_launch(void* const* d_in, const int* in_sizes, int n_in,
                              void* d_out, int out_size, void* d_ws, size_t ws_size,
                              hipStream_t stream) {
    (void)in_sizes; (void)n_in; (void)out_size; (void)ws_size;
    const float* x     = (const float*)d_in[0];
    const float* wq    = (const float*)d_in[1];
    const float* wk    = (const float*)d_in[2];
    const float* wv    = (const float*)d_in[3];
    const float* wproj = (const float*)d_in[4];
    const float* qg    = (const float*)d_in[5];

    char* ws = (char*)d_ws;
    ushort_t* xb     = (ushort_t*)ws;                               // 4096x2048 bf16 = 16 MB
    ushort_t* wqkvb  = (ushort_t*)(ws + 16777216);                  // 3072x2048 bf16 = 12 MB
    ushort_t* wprojb = (ushort_t*)(ws + 16777216 + 12582912);       // 2048x2048 bf16 = 8 MB
    float*    cqkv   = (float*)(ws + 16777216 + 12582912 + 8388608);// 4096x3072 f32 = 48 MB
    ushort_t* yb     = (ushort_t*)cqkv;                             // aliased: yb written after cqkv consumed
    char* p2 = ws + 16777216 + 12582912 + 8388608 + 50331648;
    ushort_t* qb = (ushort_t*)p2;                                   // 16 MB
    ushort_t* kb = (ushort_t*)(p2 + 16777216);                      // 4 MB
    ushort_t* vb = (ushort_t*)(p2 + 16777216 + 4194304);            // 4 MB

    cast_f32_bf16<<<8192, 256, 0, stream>>>(x, xb, 2097152);
    cast_f32_bf16<<<4096, 256, 0, stream>>>(wq, wqkvb, 1048576);
    cast_f32_bf16<<<1024, 256, 0, stream>>>(wk, wqkvb + 4194304, 262144);
    cast_f32_bf16<<<1024, 256, 0, stream>>>(wv, wqkvb + 5242880, 262144);
    cast_f32_bf16<<<4096, 256, 0, stream>>>(wproj, wprojb, 1048576);

    gemm_bt<<<dim3(24, 32), 256, 0, stream>>>(xb, wqkvb, cqkv, 4096, 3072, 2048);
    normrope<<<98304, 64, 0, stream>>>(cqkv, qg, qb, kb, vb);
    attn<<<dim3(32, 32), 256, 0, stream>>>(qb, kb, vb, yb);
    gemm_bt<<<dim3(16, 32), 256, 0, stream>>>(yb, wprojb, (float*)d_out, 4096, 2048, 2048);
}

// Round 4
// 230.134 us; speedup vs baseline: 1.6255x; 1.6255x over previous
//
#include <hip/hip_runtime.h>
#include <hip/hip_bf16.h>
#include <stdint.h>

#define DIM 2048
#define NH 16
#define NKV 4
#define HD 128
#define BATCH 2
#define SEQ 2048
#define NQKV (DIM + 2*NKV*HD)   // 3072

typedef unsigned short ushort_t;
typedef __attribute__((ext_vector_type(8))) short short8;
typedef __attribute__((ext_vector_type(4))) float f32x4;
typedef __attribute__((ext_vector_type(16))) float f32x16;

__device__ inline ushort_t f2b(float f) {
    union { float f; uint32_t u; } v; v.f = f;
    uint32_t r = (v.u + 0x7fffu + ((v.u >> 16) & 1u)) >> 16;
    return (ushort_t)r;
}

__global__ void cast_f32_bf16(const float* __restrict__ in, ushort_t* __restrict__ out, int n4) {
    int i = blockIdx.x * blockDim.x + threadIdx.x;
    if (i < n4) {
        float4 v = ((const float4*)in)[i];
        ushort4 o;
        o.x = f2b(v.x); o.y = f2b(v.y); o.z = f2b(v.z); o.w = f2b(v.w);
        ((ushort4*)out)[i] = o;
    }
}

__device__ inline void gload_lds16(const ushort_t* g, ushort_t* l) {
    __builtin_amdgcn_global_load_lds((const __attribute__((address_space(1))) void*)g,
                                     (__attribute__((address_space(3))) void*)l, 16, 0, 0);
}

// C[m][n] = sum_k A[m][k] * B[n][k]   (A: MxK row-major bf16, B: NxK row-major bf16, C fp32)
__launch_bounds__(256, 2)
__global__ void gemm_bt(const ushort_t* __restrict__ A, const ushort_t* __restrict__ Bm,
                        float* __restrict__ C, int M, int N, int K) {
    __shared__ ushort_t lA[128 * 32];
    __shared__ ushort_t lB[128 * 32];
    const int t = threadIdx.x;
    const int lane = t & 63;
    const int w = t >> 6;
    const int wr = w >> 1, wc = w & 1;
    const int g = lane >> 4, l16 = lane & 15;
    const int m0 = blockIdx.y * 128, n0 = blockIdx.x * 128;

    f32x4 acc[4][4];
#pragma unroll
    for (int i = 0; i < 4; i++)
#pragma unroll
        for (int j = 0; j < 4; j++) acc[i][j] = (f32x4){0, 0, 0, 0};

    const int row_a = t >> 2;          // 0..63
    const int col_a = (t & 3) * 8;
    const int nk = K >> 5;

    for (int kt = 0; kt < nk; ++kt) {
        const int k0 = kt * 32;
        gload_lds16(A + (size_t)(m0 + row_a) * K + k0 + col_a,       lA + t * 8);
        gload_lds16(A + (size_t)(m0 + 64 + row_a) * K + k0 + col_a,  lA + 2048 + t * 8);
        gload_lds16(Bm + (size_t)(n0 + row_a) * K + k0 + col_a,      lB + t * 8);
        gload_lds16(Bm + (size_t)(n0 + 64 + row_a) * K + k0 + col_a, lB + 2048 + t * 8);
        __syncthreads();
        short8 af[4], bf[4];
#pragma unroll
        for (int i = 0; i < 4; i++) {
            af[i] = *(const short8*)(lA + (wr * 64 + i * 16 + l16) * 32 + g * 8);
            bf[i] = *(const short8*)(lB + (wc * 64 + i * 16 + l16) * 32 + g * 8);
        }
#pragma unroll
        for (int i = 0; i < 4; i++)
#pragma unroll
            for (int j = 0; j < 4; j++)
                acc[i][j] = __builtin_amdgcn_mfma_f32_16x16x32_bf16(af[i], bf[j], acc[i][j], 0, 0, 0);
        __syncthreads();
    }
#pragma unroll
    for (int i = 0; i < 4; i++)
#pragma unroll
        for (int j = 0; j < 4; j++) {
            int rb = m0 + wr * 64 + i * 16 + g * 4;
            int cb = n0 + wc * 64 + j * 16 + l16;
#pragma unroll
            for (int r = 0; r < 4; r++)
                C[(size_t)(rb + r) * N + cb] = acc[i][j][r];
        }
}

// one wave per (token, head20): h20 in [0,16)=q, [16,20)=k   (v handled by vtrans)
__global__ void normrope(const float* __restrict__ cq, const float* __restrict__ qgain,
                         ushort_t* __restrict__ qb, ushort_t* __restrict__ kb) {
    int bidx = blockIdx.x;
    int h20 = bidx % 20;
    int tok = bidx / 20;            // b*SEQ + s
    int s = tok % SEQ;
    int b = tok / SEQ;
    int lane = threadIdx.x;         // 0..63
    const float* row = cq + (size_t)tok * NQKV + h20 * HD;
    float x1 = row[lane];
    float x2 = row[lane + 64];
    float ss = x1 * x1 + x2 * x2;
#pragma unroll
    for (int off = 32; off; off >>= 1) ss += __shfl_xor(ss, off, 64);
    float r = rsqrtf(ss * (1.0f / 128.0f) + 1.1920929e-07f);
    x1 *= r; x2 *= r;
    float inv = exp2f(-(float)lane * (13.287712379549449f / 64.0f));
    float ang = (float)s * inv;
    float c = cosf(ang), sn = sinf(ang);
    float o1 = x1 * c + x2 * sn;
    float o2 = -x1 * sn + x2 * c;
    if (h20 < NH) {
        float gsc = qgain[h20] * 0.08838834764831845f;   // gain * 1/sqrt(HD)
        o1 *= gsc; o2 *= gsc;
        ushort_t* dst = qb + ((size_t)(b * NH + h20) * SEQ + s) * HD;
        dst[lane] = f2b(o1); dst[lane + 64] = f2b(o2);
    } else {
        int kvh = h20 - NH;
        ushort_t* dst = kb + ((size_t)(b * NKV + kvh) * SEQ + s) * HD;
        dst[lane] = f2b(o1); dst[lane + 64] = f2b(o2);
    }
}

// V transpose+cast: cqkv[tok][2560 + kvh*128 + d] (f32) -> vt[(b*NKV+kvh)*HD + d][s] (bf16)
__global__ void vtrans(const float* __restrict__ cqkv, ushort_t* __restrict__ vt) {
    __shared__ float tile[64][65];
    const int sx = blockIdx.x;          // 0..31 s-tile
    const int yy = blockIdx.y;          // 0..15: b(1b) kvh(2b) dh(1b)
    const int b = yy >> 3, kvh = (yy >> 1) & 3, dh = yy & 1;
    const int s0 = sx * 64;
    const int t = threadIdx.x;
    {
        const int sl = t >> 2, dc = (t & 3) * 16;
        const float* src = cqkv + (size_t)(b * SEQ + s0 + sl) * NQKV
                           + (DIM + NKV * HD) + kvh * HD + dh * 64 + dc;
#pragma unroll
        for (int jj = 0; jj < 4; jj++) {
            float4 v = *(const float4*)(src + jj * 4);
            tile[sl][dc + jj * 4 + 0] = v.x;
            tile[sl][dc + jj * 4 + 1] = v.y;
            tile[sl][dc + jj * 4 + 2] = v.z;
            tile[sl][dc + jj * 4 + 3] = v.w;
        }
    }
    __syncthreads();
    {
        const int dl = t >> 2, sc = (t & 3) * 16;
        ushort_t* dst = vt + (size_t)((b * NKV + kvh) * HD + dh * 64 + dl) * SEQ + s0 + sc;
        short8 o0, o1;
#pragma unroll
        for (int ii = 0; ii < 8; ii++) {
            o0[ii] = (short)f2b(tile[sc + ii][dl]);
            o1[ii] = (short)f2b(tile[sc + 8 + ii][dl]);
        }
        *(short8*)(dst) = o0;
        *(short8*)(dst + 8) = o1;
    }
}

#define KVB 64

// 32x32 swapped-QK^T flash attention, 4 warps x 32 q-rows.
// K LDS [64 kv][128 d]: 16B chunk c -> c ^ (row&15), staged via pre-swizzled global src.
// V^T LDS [128 d][64 kv]: 16B chunk c -> c ^ (row&7), from global vt (pre-transposed).
// P->A-frag exchange via __shfl_xor(.,32) (defined semantics; no inline asm anywhere).
__launch_bounds__(256, 2)
__global__ void attn(const ushort_t* __restrict__ qbuf, const ushort_t* __restrict__ kbuf,
                     const ushort_t* __restrict__ vtbuf, ushort_t* __restrict__ ybuf) {
    __shared__ ushort_t Klds[KVB * HD];
    __shared__ ushort_t Vlds[HD * KVB];

    const int idx = blockIdx.x;
    const int xcd = idx & 7;
    const int j = idx >> 3;
    const int bh = xcd * 4 + (j & 3);     // 4 bh per XCD -> K/V L2 resident
    const int qt = 15 - (j >> 2);         // heavy q-tiles dispatched first
    const int b = bh >> 4, hh = bh & 15;
    const int kvh = hh >> 2;
    const int t = threadIdx.x;
    const int w = t >> 6, lane = t & 63;
    const int l31 = lane & 31, hf = lane >> 5;
    const int q0 = qt * 128;
    const int qbase = q0 + w * 32;

    const ushort_t* Qp = qbuf + (size_t)(b * NH + hh) * SEQ * HD;
    const ushort_t* Kp = kbuf + (size_t)(b * NKV + kvh) * SEQ * HD;
    const ushort_t* Vtp = vtbuf + (size_t)(b * NKV + kvh) * HD * SEQ;

    // Q fragments: B-operand of QK^T. aq[dc][j] = Q[qbase+l31][dc*16 + hf*8 + j]
    short8 aq[8];
#pragma unroll
    for (int dc = 0; dc < 8; dc++)
        aq[dc] = *(const short8*)(Qp + (size_t)(qbase + l31) * HD + dc * 16 + hf * 8);

    f32x16 y[4];
#pragma unroll
    for (int db = 0; db < 4; db++)
#pragma unroll
        for (int r = 0; r < 16; r++) y[db][r] = 0.0f;
    float mrun = -1e30f, lrun = 0.0f;

    // staging addresses
    const int krow = t >> 4;                               // + i*16
    const int kcol = ((t & 15) ^ (t >> 4)) * 8;            // source chunk = c ^ (row&15)
    const int vrow = t >> 3;                               // + i*32
    const int vcol = ((t & 7) ^ ((t >> 3) & 7)) * 8;       // source chunk = c ^ (row&7)

    const int ntiles = q0 / 64 + 2;
    for (int kt = 0; kt < ntiles; ++kt) {
        const int kv0 = kt * KVB;
        __syncthreads();
#pragma unroll
        for (int i = 0; i < 4; i++) {
            gload_lds16(Kp + (size_t)(kv0 + i * 16 + krow) * HD + kcol, Klds + i * 2048 + t * 8);
            gload_lds16(Vtp + (size_t)(i * 32 + vrow) * SEQ + kv0 + vcol, Vlds + i * 2048 + t * 8);
        }
        __syncthreads();
        if (kv0 > qbase + 31) continue;   // warp-uniform; barrier counts stay matched

        // ---- QK^T (swapped): S^T[kv][q]; lane: q = qbase+l31; rows kv = blk*32 + (r&3)+8*(r>>2)+4*hf
        f32x16 s0v, s1v;
#pragma unroll
        for (int r = 0; r < 16; r++) { s0v[r] = 0.0f; s1v[r] = 0.0f; }
#pragma unroll
        for (int dc = 0; dc < 8; dc++) {
            short8 ak0 = *(const short8*)(Klds + (size_t)(l31) * HD      + (((dc * 2 + hf) ^ (l31 & 15)) * 8));
            short8 ak1 = *(const short8*)(Klds + (size_t)(32 + l31) * HD + (((dc * 2 + hf) ^ (l31 & 15)) * 8));
            s0v = __builtin_amdgcn_mfma_f32_32x32x16_bf16(ak0, aq[dc], s0v, 0, 0, 0);
            s1v = __builtin_amdgcn_mfma_f32_32x32x16_bf16(ak1, aq[dc], s1v, 0, 0, 0);
        }

        // ---- causal mask ----
        const int qabs = qbase + l31;
        if (kv0 + 63 > qbase) {
#pragma unroll
            for (int r = 0; r < 16; r++) {
                int kvr = kv0 + (r & 3) + 8 * (r >> 2) + 4 * hf;
                if (kvr > qabs)      s0v[r] = -1e30f;
                if (kvr + 32 > qabs) s1v[r] = -1e30f;
            }
        }

        // ---- softmax (per-lane q), online with defer-max ----
        float mt = -1e30f;
#pragma unroll
        for (int r = 0; r < 16; r++) mt = fmaxf(mt, fmaxf(s0v[r], s1v[r]));
        mt = fmaxf(mt, __shfl_xor(mt, 32, 64));
        if (!__all(mt <= mrun + 8.0f)) {
            float mn = fmaxf(mrun, mt);
            float al = __expf(mrun - mn);
            mrun = mn;
            lrun *= al;
#pragma unroll
            for (int r = 0; r < 16; r++) {
                float alr = __shfl(al, (r & 3) + 8 * (r >> 2) + 4 * hf, 64);
#pragma unroll
                for (int db = 0; db < 4; db++) y[db][r] *= alr;
            }
        }
        float sum = 0.0f;
#pragma unroll
        for (int r = 0; r < 16; r++) {
            float p0 = __expf(s0v[r] - mrun);
            float p1 = __expf(s1v[r] - mrun);
            s0v[r] = p0; s1v[r] = p1;
            sum += p0 + p1;
        }
        sum += __shfl_xor(sum, 32, 64);
        lrun += sum;

        // ---- P -> A-fragments via pack + lane^32 exchange ----
        // pa[ks=2blk+ks2] elem j = P[q][kv = blk*32 + ks2*16 + hf*8 + j]
        // own regs (lane): s[blk][8ks2+c]      -> kv = blk*32 + ks2*16 + 4hf + c      (c=0..3)
        //                  s[blk][8ks2+4+c]    -> kv = blk*32 + ks2*16 + 8 + 4hf + c
        // hf=0 needs: j=0..3 own low; j=4..7 partner(hf=1) low.
        // hf=1 needs: j=0..3 partner(hf=0) high; j=4..7 own high.
        union PW { short8 v; uint32_t wd[4]; } pa[4];
#pragma unroll
        for (int blk = 0; blk < 2; blk++) {
#pragma unroll
            for (int ks2 = 0; ks2 < 2; ks2++) {
#pragma unroll
                for (int t2 = 0; t2 < 2; t2++) {
                    float a0 = blk ? s1v[8 * ks2 + 2 * t2]         : s0v[8 * ks2 + 2 * t2];
                    float a1 = blk ? s1v[8 * ks2 + 2 * t2 + 1]     : s0v[8 * ks2 + 2 * t2 + 1];
                    float b0 = blk ? s1v[8 * ks2 + 4 + 2 * t2]     : s0v[8 * ks2 + 4 + 2 * t2];
                    float b1 = blk ? s1v[8 * ks2 + 4 + 2 * t2 + 1] : s0v[8 * ks2 + 4 + 2 * t2 + 1];
                    uint32_t pw = (uint32_t)f2b(a0) | ((uint32_t)f2b(a1) << 16);  // low pair
                    uint32_t qw = (uint32_t)f2b(b0) | ((uint32_t)f2b(b1) << 16);  // high pair
                    uint32_t send = hf ? pw : qw;
                    uint32_t recv = (uint32_t)__shfl_xor((int)send, 32, 64);
                    pa[blk * 2 + ks2].wd[t2]     = hf ? recv : pw;
                    pa[blk * 2 + ks2].wd[t2 + 2] = hf ? qw : recv;
                }
            }
        }

        // ---- PV: y[db] += sum_ks pa[ks] x V^T-frag ----
#pragma unroll
        for (int ks = 0; ks < 4; ks++) {
#pragma unroll
            for (int db = 0; db < 4; db++) {
                short8 bv = *(const short8*)(Vlds + (size_t)(db * 32 + l31) * KVB
                                             + (((ks * 2 + hf) ^ (l31 & 7)) * 8));
                y[db] = __builtin_amdgcn_mfma_f32_32x32x16_bf16(pa[ks].v, bv, y[db], 0, 0, 0);
            }
        }
    }

    // ---- epilogue: normalize + store. y: q = qbase + (r&3)+8*(r>>2)+4*hf, d = db*32+l31 ----
    float linv = 1.0f / lrun;
    ushort_t* Yp = ybuf + (size_t)b * SEQ * DIM + hh * HD;
#pragma unroll
    for (int r = 0; r < 16; r++) {
        int qloc = (r & 3) + 8 * (r >> 2) + 4 * hf;
        float lr = __shfl(linv, qloc, 64);
        int q = qbase + qloc;
#pragma unroll
        for (int db = 0; db < 4; db++)
            Yp[(size_t)q * DIM + db * 32 + l31] = f2b(y[db][r] * lr);
    }
}

extern "C" void kernel_launch(void* const* d_in, const int* in_sizes, int n_in,
                              void* d_out, int out_size, void* d_ws, size_t ws_size,
                              hipStream_t stream) {
    (void)in_sizes; (void)n_in; (void)out_size; (void)ws_size;
    const float* x     = (const float*)d_in[0];
    const float* wq    = (const float*)d_in[1];
    const float* wk    = (const float*)d_in[2];
    const float* wv    = (const float*)d_in[3];
    const float* wproj = (const float*)d_in[4];
    const float* qg    = (const float*)d_in[5];

    char* ws = (char*)d_ws;
    ushort_t* xb     = (ushort_t*)ws;                               // 4096x2048 bf16 = 16 MB
    ushort_t* wqkvb  = (ushort_t*)(ws + 16777216);                  // 3072x2048 bf16 = 12 MB
    ushort_t* wprojb = (ushort_t*)(ws + 16777216 + 12582912);       // 2048x2048 bf16 = 8 MB
    float*    cqkv   = (float*)(ws + 16777216 + 12582912 + 8388608);// 4096x3072 f32 = 48 MB
    ushort_t* yb     = (ushort_t*)cqkv;                             // aliased: yb written after cqkv consumed
    char* p2 = ws + 16777216 + 12582912 + 8388608 + 50331648;
    ushort_t* qb  = (ushort_t*)p2;                                  // 16 MB
    ushort_t* kb  = (ushort_t*)(p2 + 16777216);                     // 4 MB
    ushort_t* vtb = (ushort_t*)(p2 + 16777216 + 4194304);           // 4 MB (V^T)

    cast_f32_bf16<<<8192, 256, 0, stream>>>(x, xb, 2097152);
    cast_f32_bf16<<<4096, 256, 0, stream>>>(wq, wqkvb, 1048576);
    cast_f32_bf16<<<1024, 256, 0, stream>>>(wk, wqkvb + 4194304, 262144);
    cast_f32_bf16<<<1024, 256, 0, stream>>>(wv, wqkvb + 5242880, 262144);
    cast_f32_bf16<<<4096, 256, 0, stream>>>(wproj, wprojb, 1048576);

    gemm_bt<<<dim3(24, 32), 256, 0, stream>>>(xb, wqkvb, cqkv, 4096, 3072, 2048);
    normrope<<<81920, 64, 0, stream>>>(cqkv, qg, qb, kb);
    vtrans<<<dim3(32, 16), 256, 0, stream>>>(cqkv, vtb);
    attn<<<512, 256, 0, stream>>>(qb, kb, vtb, yb);
    gemm_bt<<<dim3(16, 32), 256, 0, stream>>>(yb, wprojb, (float*)d_out, 4096, 2048, 2048);
}